// Round 1
// baseline (585.301 us; speedup 1.0000x reference)
//
#include <hip/hip_runtime.h>
#include <hip/hip_bf16.h>

#define N_NODES 25000
#define N_EDGES 400000
#define IN_CH 1024
#define FC 128
#define ADD_CH 20
#define XCH 148   // FC + ADD
#define MID 37
#define OUT_CH 3

// ---------------- CSR build ----------------

__global__ __launch_bounds__(256) void hist_kernel(const int* __restrict__ edges,
                                                   int* __restrict__ deg) {
    int e = blockIdx.x * 256 + threadIdx.x;
    if (e < N_EDGES) atomicAdd(&deg[edges[N_EDGES + e]], 1);
}

__global__ __launch_bounds__(256) void scan_kernel(const int* __restrict__ deg,
                                                   int* __restrict__ row_start) {
    __shared__ int s[256];
    __shared__ int carry_s;
    int t = threadIdx.x;
    if (t == 0) carry_s = 0;
    __syncthreads();
    int nchunk = (N_NODES + 255) / 256;
    for (int c = 0; c < nchunk; ++c) {
        int idx = c * 256 + t;
        int v = (idx < N_NODES) ? deg[idx] : 0;
        s[t] = v;
        __syncthreads();
        int x = v;
        for (int off = 1; off < 256; off <<= 1) {
            int add = (t >= off) ? s[t - off] : 0;
            __syncthreads();
            x += add;
            s[t] = x;
            __syncthreads();
        }
        int carry = carry_s;
        if (idx < N_NODES) row_start[idx] = carry + x - v;  // exclusive prefix
        __syncthreads();
        if (t == 255) carry_s = carry + x;
        __syncthreads();
    }
}

__global__ __launch_bounds__(256) void fill_kernel(const int* __restrict__ edges,
                                                   const int* __restrict__ row_start,
                                                   int* __restrict__ cursor,
                                                   int* __restrict__ col) {
    int e = blockIdx.x * 256 + threadIdx.x;
    if (e < N_EDGES) {
        int d = edges[N_EDGES + e];
        int pos = atomicAdd(&cursor[d], 1);
        col[row_start[d] + pos] = edges[e];
    }
}

// ---------------- GEMM: P[N,256] = features @ [Wl;Wr]^T ----------------
// cols 0..127 : Y = features @ Wl^T (neighbor path, pre-aggregation)
// cols 128..255: Z = features @ Wr^T (root path)

#define BM 64
#define BN 64
#define BK 32
#define LDA (BM + 4)

__global__ __launch_bounds__(256) void gemm_kernel(const float* __restrict__ A,
                                                   const float* __restrict__ Wl,
                                                   const float* __restrict__ Wr,
                                                   float* __restrict__ P) {
    __shared__ float As[BK][LDA];
    __shared__ float Bs[BK][LDA];
    int t = threadIdx.x;
    int tx = t & 15, ty = t >> 4;
    int m0 = blockIdx.x * BM;
    int n0 = blockIdx.y * BN;
    float acc[4][4] = {};
    for (int k0 = 0; k0 < IN_CH; k0 += BK) {
        #pragma unroll
        for (int l = 0; l < 2; ++l) {
            int lin = t + l * 256;        // float4 index within 64x32 tile
            int row = lin >> 3;           // 8 float4 per row
            int kk = (lin & 7) << 2;
            int gr = m0 + row; if (gr >= N_NODES) gr = N_NODES - 1;
            const float4 av = *(const float4*)&A[gr * IN_CH + k0 + kk];
            As[kk + 0][row] = av.x;
            As[kk + 1][row] = av.y;
            As[kk + 2][row] = av.z;
            As[kk + 3][row] = av.w;
            int br = n0 + row;
            const float* Wp = (br < FC) ? &Wl[br * IN_CH] : &Wr[(br - FC) * IN_CH];
            const float4 bv = *(const float4*)&Wp[k0 + kk];
            Bs[kk + 0][row] = bv.x;
            Bs[kk + 1][row] = bv.y;
            Bs[kk + 2][row] = bv.z;
            Bs[kk + 3][row] = bv.w;
        }
        __syncthreads();
        #pragma unroll
        for (int k = 0; k < BK; ++k) {
            float4 a4 = *(const float4*)&As[k][ty * 4];
            float4 b4 = *(const float4*)&Bs[k][tx * 4];
            float av[4] = {a4.x, a4.y, a4.z, a4.w};
            float bv[4] = {b4.x, b4.y, b4.z, b4.w};
            #pragma unroll
            for (int i = 0; i < 4; ++i)
                #pragma unroll
                for (int j = 0; j < 4; ++j)
                    acc[i][j] += av[i] * bv[j];
        }
        __syncthreads();
    }
    #pragma unroll
    for (int i = 0; i < 4; ++i) {
        int r = m0 + ty * 4 + i;
        if (r < N_NODES) {
            float4 v = make_float4(acc[i][0], acc[i][1], acc[i][2], acc[i][3]);
            *(float4*)&P[r * 256 + n0 + tx * 4] = v;
        }
    }
}

// ---------------- fused gather + SAGE combine + MLP tail ----------------
// one wave (64 lanes) per node; 4 nodes per block

__global__ __launch_bounds__(256) void fused_tail(const float* __restrict__ P,
                                                  const int* __restrict__ deg,
                                                  const int* __restrict__ row_start,
                                                  const int* __restrict__ col,
                                                  const float* __restrict__ addf,
                                                  const float* __restrict__ bl,
                                                  const float* __restrict__ W1,
                                                  const float* __restrict__ b1,
                                                  const float* __restrict__ W2,
                                                  const float* __restrict__ b2,
                                                  const float* __restrict__ gamma,
                                                  const float* __restrict__ beta,
                                                  const float* __restrict__ rmean,
                                                  const float* __restrict__ rvar,
                                                  float* __restrict__ out) {
    __shared__ float xbuf[4][XCH + 4];
    __shared__ float hbuf[4][MID + 3];
    int w = threadIdx.x >> 6;
    int lane = threadIdx.x & 63;
    int n = blockIdx.x * 4 + w;
    bool valid = (n < N_NODES);
    float acc0 = 0.f, acc1 = 0.f;
    int d = 0, start = 0;
    if (valid) { d = deg[n]; start = row_start[n]; }
    for (int i = 0; i < d; ++i) {
        int s = col[start + i];
        acc0 += P[s * 256 + lane];
        acc1 += P[s * 256 + 64 + lane];
    }
    if (valid) {
        float invd = 1.0f / (float)(d > 1 ? d : 1);
        float x0 = acc0 * invd + bl[lane]      + P[n * 256 + 128 + lane];
        float x1 = acc1 * invd + bl[64 + lane] + P[n * 256 + 192 + lane];
        x0 = (x0 >= 0.f) ? x0 : 0.01f * x0;
        x1 = (x1 >= 0.f) ? x1 : 0.01f * x1;
        xbuf[w][lane] = x0;
        xbuf[w][64 + lane] = x1;
        if (lane < ADD_CH) xbuf[w][FC + lane] = addf[n * ADD_CH + lane];
    }
    __syncthreads();
    if (valid && lane < MID) {
        float h = b1[lane];
        for (int k = 0; k < XCH; ++k) h += W1[lane * XCH + k] * xbuf[w][k];
        h = fmaxf(h, 0.0f);
        h = gamma[lane] * (h - rmean[lane]) * rsqrtf(rvar[lane] + 1e-5f) + beta[lane];
        hbuf[w][lane] = h;
    }
    __syncthreads();
    if (valid && lane < OUT_CH) {
        float o = b2[lane];
        for (int j = 0; j < MID; ++j) o += W2[lane * MID + j] * hbuf[w][j];
        out[n * OUT_CH + lane] = o;
    }
}

// ---------------- launch ----------------

extern "C" void kernel_launch(void* const* d_in, const int* in_sizes, int n_in,
                              void* d_out, int out_size, void* d_ws, size_t ws_size,
                              hipStream_t stream) {
    const float* features = (const float*)d_in[0];
    const int*   edges    = (const int*)d_in[1];
    // d_in[2] edges2, d_in[3] edge_features are unused by the reference
    const float* addf     = (const float*)d_in[4];
    const float* Wl       = (const float*)d_in[5];
    const float* bl       = (const float*)d_in[6];
    const float* Wr       = (const float*)d_in[7];
    const float* W1       = (const float*)d_in[8];
    const float* b1       = (const float*)d_in[9];
    const float* W2       = (const float*)d_in[10];
    const float* b2       = (const float*)d_in[11];
    const float* gamma    = (const float*)d_in[12];
    const float* beta     = (const float*)d_in[13];
    const float* rmean    = (const float*)d_in[14];
    const float* rvar     = (const float*)d_in[15];
    float* out = (float*)d_out;

    char* ws = (char*)d_ws;
    size_t off = 0;
    float* P = (float*)(ws + off);        off += (size_t)N_NODES * 256 * 4;
    int* deg = (int*)(ws + off);          off += (size_t)N_NODES * 4;
    int* cursor = (int*)(ws + off);       off += (size_t)N_NODES * 4;
    int* row_start = (int*)(ws + off);    off += (size_t)N_NODES * 4;
    int* col = (int*)(ws + off);          off += (size_t)N_EDGES * 4;

    // zero deg + cursor (contiguous)
    hipMemsetAsync(deg, 0, (size_t)2 * N_NODES * 4, stream);

    int eb = (N_EDGES + 255) / 256;
    hist_kernel<<<eb, 256, 0, stream>>>(edges, deg);
    scan_kernel<<<1, 256, 0, stream>>>(deg, row_start);
    fill_kernel<<<eb, 256, 0, stream>>>(edges, row_start, cursor, col);

    dim3 ggrid((N_NODES + BM - 1) / BM, 256 / BN);
    gemm_kernel<<<ggrid, 256, 0, stream>>>(features, Wl, Wr, P);

    fused_tail<<<(N_NODES + 3) / 4, 256, 0, stream>>>(P, deg, row_start, col, addf, bl,
                                                      W1, b1, W2, b2, gamma, beta,
                                                      rmean, rvar, out);
}

// Round 3
// 369.985 us; speedup vs baseline: 1.5820x; 1.5820x over previous
//
#include <hip/hip_runtime.h>
#include <hip/hip_bf16.h>

#define N_NODES 25000
#define N_EDGES 400000
#define IN_CH 1024
#define FC 128
#define ADD_CH 20
#define XCH 148   // FC + ADD
#define MID 37
#define OUT_CH 3

typedef short bf16x8 __attribute__((ext_vector_type(8)));
typedef float f32x4 __attribute__((ext_vector_type(4)));

__device__ __forceinline__ unsigned int f2bf(float x) {
    unsigned int u = __builtin_bit_cast(unsigned int, x);
    unsigned int lsb = (u >> 16) & 1u;
    u += 0x7fffu + lsb;           // round-to-nearest-even
    return u >> 16;
}
__device__ __forceinline__ unsigned int pkbf(float a, float b) {
    return f2bf(a) | (f2bf(b) << 16);
}
__device__ __forceinline__ float bflo(unsigned int v) {
    return __builtin_bit_cast(float, v << 16);
}
__device__ __forceinline__ float bfhi(unsigned int v) {
    return __builtin_bit_cast(float, v & 0xffff0000u);
}

// ---------------- CSR build ----------------

__global__ __launch_bounds__(256) void hist_kernel(const int* __restrict__ edges,
                                                   int* __restrict__ deg) {
    int e = blockIdx.x * 256 + threadIdx.x;
    if (e < N_EDGES) atomicAdd(&deg[edges[N_EDGES + e]], 1);
}

// 1024-thread single-block scan: per-thread serial chunk + wave shuffle scan
__global__ __launch_bounds__(1024) void scan_kernel(const int* __restrict__ deg,
                                                    int* __restrict__ row_start) {
    __shared__ int wsum[16];
    int t = threadIdx.x;
    const int PER = 25;  // 1024*25 >= 25000
    int base = t * PER;
    int vals[PER];
    int s = 0;
    #pragma unroll
    for (int i = 0; i < PER; ++i) {
        int idx = base + i;
        int v = (idx < N_NODES) ? deg[idx] : 0;
        vals[i] = s;       // thread-local exclusive prefix
        s += v;
    }
    int lane = t & 63, w = t >> 6;
    int x = s;
    #pragma unroll
    for (int off = 1; off < 64; off <<= 1) {
        int y = __shfl_up(x, off);
        if (lane >= off) x += y;
    }
    if (lane == 63) wsum[w] = x;
    __syncthreads();
    if (t == 0) {
        int a = 0;
        #pragma unroll
        for (int j = 0; j < 16; ++j) { int y = wsum[j]; wsum[j] = a; a += y; }
    }
    __syncthreads();
    int thread_excl = x - s + wsum[w];
    #pragma unroll
    for (int i = 0; i < PER; ++i) {
        int idx = base + i;
        if (idx < N_NODES) row_start[idx] = thread_excl + vals[i];
    }
}

__global__ __launch_bounds__(256) void fill_kernel(const int* __restrict__ edges,
                                                   const int* __restrict__ row_start,
                                                   int* __restrict__ cursor,
                                                   int* __restrict__ col) {
    int e = blockIdx.x * 256 + threadIdx.x;
    if (e < N_EDGES) {
        int d = edges[N_EDGES + e];
        int pos = atomicAdd(&cursor[d], 1);
        col[row_start[d] + pos] = edges[e];
    }
}

// ---------------- W -> bf16 pre-convert ----------------
// Wb[256][1024]: rows 0..127 = Wl, 128..255 = Wr
__global__ __launch_bounds__(256) void cvtw_kernel(const float* __restrict__ Wl,
                                                   const float* __restrict__ Wr,
                                                   ushort* __restrict__ Wb) {
    int i = blockIdx.x * 256 + threadIdx.x;  // float4 index, 65536 total
    const float* src = (i < 32768) ? Wl : Wr;
    int j = (i < 32768) ? i : i - 32768;
    float4 v = *(const float4*)&src[(size_t)j * 4];
    uint2 pk;
    pk.x = pkbf(v.x, v.y);
    pk.y = pkbf(v.z, v.w);
    *(uint2*)&Wb[(size_t)i * 4] = pk;
}

// ---------------- MFMA GEMM: P[N][256] (bf16) = feat @ [Wl;Wr]^T ----------------
// A-operand = weights (channels), B-operand = features (nodes).
// D[ch][node]: lane holds node = lane&15, channels quad*4 + reg (4 consecutive
// channels -> one 8B bf16x4 store per fragment).

#define GBM 128   // nodes per block
#define LDT 56    // LDS row stride in ushorts (112 B: 16B-aligned frags, 2-way banks)

__global__ __launch_bounds__(256) void gemm_kernel(const float* __restrict__ A,
                                                   const ushort* __restrict__ Wb,
                                                   ushort* __restrict__ P) {
    __shared__ __align__(16) ushort Ws[256][LDT];
    __shared__ __align__(16) ushort Fs[GBM][LDT];
    int t = threadIdx.x;
    int m0 = blockIdx.x * GBM;
    int w = t >> 6, lane = t & 63;
    int l15 = lane & 15, q = lane >> 4, q8 = q * 8;
    f32x4 acc[4][8] = {};
    int wf = t & 3, wr = t >> 2;   // W staging: 4x16B chunks per row, 64 rows/pass
    int ff = t & 7, fr = t >> 3;   // F staging: 8x float4 per row, 32 rows/pass
    for (int k0 = 0; k0 < IN_CH; k0 += 32) {
        #pragma unroll
        for (int p = 0; p < 4; ++p) {
            int r = wr + p * 64;
            uint4 wv = *(const uint4*)&Wb[(size_t)r * IN_CH + k0 + wf * 8];
            *(uint4*)&Ws[r][wf * 8] = wv;
        }
        #pragma unroll
        for (int p = 0; p < 4; ++p) {
            int r = fr + p * 32;
            int gr = m0 + r;
            if (gr >= N_NODES) gr = N_NODES - 1;
            float4 fv = *(const float4*)&A[(size_t)gr * IN_CH + k0 + ff * 4];
            uint2 pk;
            pk.x = pkbf(fv.x, fv.y);
            pk.y = pkbf(fv.z, fv.w);
            *(uint2*)&Fs[r][ff * 4] = pk;
        }
        __syncthreads();
        bf16x8 bfr[8];
        #pragma unroll
        for (int nf = 0; nf < 8; ++nf)
            bfr[nf] = *(const bf16x8*)&Fs[nf * 16 + l15][q8];
        #pragma unroll
        for (int cf = 0; cf < 4; ++cf) {
            bf16x8 af = *(const bf16x8*)&Ws[w * 64 + cf * 16 + l15][q8];
            #pragma unroll
            for (int nf = 0; nf < 8; ++nf)
                acc[cf][nf] = __builtin_amdgcn_mfma_f32_16x16x32_bf16(af, bfr[nf], acc[cf][nf], 0, 0, 0);
        }
        __syncthreads();
    }
    #pragma unroll
    for (int nf = 0; nf < 8; ++nf) {
        int node = m0 + nf * 16 + l15;
        if (node < N_NODES) {
            #pragma unroll
            for (int cf = 0; cf < 4; ++cf) {
                f32x4 v = acc[cf][nf];
                uint2 pk;
                pk.x = pkbf(v[0], v[1]);
                pk.y = pkbf(v[2], v[3]);
                *(uint2*)&P[(size_t)node * 256 + w * 64 + cf * 16 + q * 4] = pk;
            }
        }
    }
}

// ---------------- fused gather + SAGE combine + MLP tail ----------------
// one wave per node, 4 nodes/block; P is bf16 (256 B per half-row gather)

__global__ __launch_bounds__(256) void fused_tail(const ushort* __restrict__ P,
                                                  const int* __restrict__ deg,
                                                  const int* __restrict__ row_start,
                                                  const int* __restrict__ col,
                                                  const float* __restrict__ addf,
                                                  const float* __restrict__ bl,
                                                  const float* __restrict__ W1,
                                                  const float* __restrict__ b1,
                                                  const float* __restrict__ W2,
                                                  const float* __restrict__ b2,
                                                  const float* __restrict__ gamma,
                                                  const float* __restrict__ beta,
                                                  const float* __restrict__ rmean,
                                                  const float* __restrict__ rvar,
                                                  float* __restrict__ out) {
    __shared__ float xbuf[4][XCH + 4];
    __shared__ float hbuf[4][MID + 3];
    int w = threadIdx.x >> 6;
    int lane = threadIdx.x & 63;
    int n = blockIdx.x * 4 + w;
    bool valid = (n < N_NODES);
    float a0 = 0.f, a1 = 0.f;
    int d = 0, st = 0;
    if (valid) { d = deg[n]; st = row_start[n]; }
    for (int i = 0; i < d; ++i) {
        int s = col[st + i];
        unsigned int v = *(const unsigned int*)&P[(size_t)s * 256 + lane * 2];
        a0 += bflo(v);
        a1 += bfhi(v);
    }
    if (valid) {
        float invd = 1.0f / (float)(d > 1 ? d : 1);
        unsigned int vr = *(const unsigned int*)&P[(size_t)n * 256 + 128 + lane * 2];
        float x0 = a0 * invd + bl[2 * lane]     + bflo(vr);
        float x1 = a1 * invd + bl[2 * lane + 1] + bfhi(vr);
        x0 = (x0 >= 0.f) ? x0 : 0.01f * x0;
        x1 = (x1 >= 0.f) ? x1 : 0.01f * x1;
        xbuf[w][2 * lane] = x0;
        xbuf[w][2 * lane + 1] = x1;
        if (lane < ADD_CH) xbuf[w][FC + lane] = addf[(size_t)n * ADD_CH + lane];
    }
    __syncthreads();
    if (valid && lane < MID) {
        float h = b1[lane];
        for (int k = 0; k < XCH; ++k) h += W1[lane * XCH + k] * xbuf[w][k];
        h = fmaxf(h, 0.0f);
        h = gamma[lane] * (h - rmean[lane]) * rsqrtf(rvar[lane] + 1e-5f) + beta[lane];
        hbuf[w][lane] = h;
    }
    __syncthreads();
    if (valid && lane < OUT_CH) {
        float o = b2[lane];
        for (int j = 0; j < MID; ++j) o += W2[lane * MID + j] * hbuf[w][j];
        out[(size_t)n * OUT_CH + lane] = o;
    }
}

// ---------------- launch ----------------

extern "C" void kernel_launch(void* const* d_in, const int* in_sizes, int n_in,
                              void* d_out, int out_size, void* d_ws, size_t ws_size,
                              hipStream_t stream) {
    const float* features = (const float*)d_in[0];
    const int*   edges    = (const int*)d_in[1];
    const float* addf     = (const float*)d_in[4];
    const float* Wl       = (const float*)d_in[5];
    const float* bl       = (const float*)d_in[6];
    const float* Wr       = (const float*)d_in[7];
    const float* W1       = (const float*)d_in[8];
    const float* b1       = (const float*)d_in[9];
    const float* W2       = (const float*)d_in[10];
    const float* b2       = (const float*)d_in[11];
    const float* gamma    = (const float*)d_in[12];
    const float* beta     = (const float*)d_in[13];
    const float* rmean    = (const float*)d_in[14];
    const float* rvar     = (const float*)d_in[15];
    float* out = (float*)d_out;

    char* ws = (char*)d_ws;
    size_t off = 0;
    ushort* P = (ushort*)(ws + off);      off += (size_t)N_NODES * 256 * 2;   // 12.8 MB
    ushort* Wb = (ushort*)(ws + off);     off += (size_t)256 * IN_CH * 2;     // 512 KB
    int* deg = (int*)(ws + off);          off += (size_t)N_NODES * 4;
    int* cursor = (int*)(ws + off);       off += (size_t)N_NODES * 4;
    int* row_start = (int*)(ws + off);    off += (size_t)N_NODES * 4;
    int* col = (int*)(ws + off);          off += (size_t)N_EDGES * 4;

    (void)hipMemsetAsync(deg, 0, (size_t)2 * N_NODES * 4, stream);  // deg + cursor

    cvtw_kernel<<<256, 256, 0, stream>>>(Wl, Wr, Wb);

    int eb = (N_EDGES + 255) / 256;
    hist_kernel<<<eb, 256, 0, stream>>>(edges, deg);
    scan_kernel<<<1, 1024, 0, stream>>>(deg, row_start);
    fill_kernel<<<eb, 256, 0, stream>>>(edges, row_start, cursor, col);

    gemm_kernel<<<(N_NODES + GBM - 1) / GBM, 256, 0, stream>>>(features, Wb, P);

    fused_tail<<<(N_NODES + 3) / 4, 256, 0, stream>>>(P, deg, row_start, col, addf, bl,
                                                      W1, b1, W2, b2, gamma, beta,
                                                      rmean, rvar, out);
}

// Round 4
// 363.870 us; speedup vs baseline: 1.6085x; 1.0168x over previous
//
#include <hip/hip_runtime.h>
#include <hip/hip_bf16.h>

#define N_NODES 25000
#define N_EDGES 400000
#define IN_CH 1024
#define FC 128
#define ADD_CH 20
#define XCH 148   // FC + ADD
#define MID 37
#define OUT_CH 3

typedef short bf16x8 __attribute__((ext_vector_type(8)));
typedef float f32x4 __attribute__((ext_vector_type(4)));

__device__ __forceinline__ unsigned int f2bf(float x) {
    unsigned int u = __builtin_bit_cast(unsigned int, x);
    unsigned int lsb = (u >> 16) & 1u;
    u += 0x7fffu + lsb;           // round-to-nearest-even
    return u >> 16;
}
__device__ __forceinline__ unsigned int pkbf(float a, float b) {
    return f2bf(a) | (f2bf(b) << 16);
}
__device__ __forceinline__ float bflo(unsigned int v) {
    return __builtin_bit_cast(float, v << 16);
}
__device__ __forceinline__ float bfhi(unsigned int v) {
    return __builtin_bit_cast(float, v & 0xffff0000u);
}

// ---------------- prep: W->bf16 convert + degree histogram + W1 transpose ----
// blocks [0,256): cvt Wl/Wr -> Wb[256][1024] bf16
// blocks [256, 256+1563): histogram of dst
// block 1819: W1t[k*37+j] = W1[j*148+k]
#define HIST_B 1563
__global__ __launch_bounds__(256) void prep_kernel(const float* __restrict__ Wl,
                                                   const float* __restrict__ Wr,
                                                   const int* __restrict__ edges,
                                                   const float* __restrict__ W1,
                                                   ushort* __restrict__ Wb,
                                                   int* __restrict__ deg,
                                                   float* __restrict__ W1t) {
    int b = blockIdx.x, t = threadIdx.x;
    if (b < 256) {
        int i = b * 256 + t;  // float4 index, 65536 total
        const float* src = (i < 32768) ? Wl : Wr;
        int j = (i < 32768) ? i : i - 32768;
        float4 v = *(const float4*)&src[(size_t)j * 4];
        uint2 pk;
        pk.x = pkbf(v.x, v.y);
        pk.y = pkbf(v.z, v.w);
        *(uint2*)&Wb[(size_t)i * 4] = pk;
    } else if (b < 256 + HIST_B) {
        int e = (b - 256) * 256 + t;
        if (e < N_EDGES) atomicAdd(&deg[edges[N_EDGES + e]], 1);
    } else {
        #pragma unroll
        for (int i = 0; i < 22; ++i) {
            int idx = i * 256 + t;
            if (idx < MID * XCH) {
                int j = idx / XCH, k = idx - j * XCH;
                W1t[k * MID + j] = W1[idx];
            }
        }
    }
}

// 1024-thread single-block scan: per-thread serial chunk + wave shuffle scan
__global__ __launch_bounds__(1024) void scan_kernel(const int* __restrict__ deg,
                                                    int* __restrict__ row_start) {
    __shared__ int wsum[16];
    int t = threadIdx.x;
    const int PER = 25;  // 1024*25 >= 25000
    int base = t * PER;
    int vals[PER];
    int s = 0;
    #pragma unroll
    for (int i = 0; i < PER; ++i) {
        int idx = base + i;
        int v = (idx < N_NODES) ? deg[idx] : 0;
        vals[i] = s;
        s += v;
    }
    int lane = t & 63, w = t >> 6;
    int x = s;
    #pragma unroll
    for (int off = 1; off < 64; off <<= 1) {
        int y = __shfl_up(x, off);
        if (lane >= off) x += y;
    }
    if (lane == 63) wsum[w] = x;
    __syncthreads();
    if (t == 0) {
        int a = 0;
        #pragma unroll
        for (int j = 0; j < 16; ++j) { int y = wsum[j]; wsum[j] = a; a += y; }
    }
    __syncthreads();
    int thread_excl = x - s + wsum[w];
    #pragma unroll
    for (int i = 0; i < PER; ++i) {
        int idx = base + i;
        if (idx < N_NODES) row_start[idx] = thread_excl + vals[i];
    }
}

__global__ __launch_bounds__(256) void fill_kernel(const int* __restrict__ edges,
                                                   const int* __restrict__ row_start,
                                                   int* __restrict__ cursor,
                                                   int* __restrict__ col) {
    int e = blockIdx.x * 256 + threadIdx.x;
    if (e < N_EDGES) {
        int d = edges[N_EDGES + e];
        int pos = atomicAdd(&cursor[d], 1);
        col[row_start[d] + pos] = edges[e];
    }
}

// ---------------- MFMA GEMM: P[N][256] (bf16) = feat @ [Wl;Wr]^T ----------------
// A-operand = weights (channels), B = features (nodes). Register-prefetch of the
// next K-tile hides HBM latency (only 1 wave/SIMD at 196 blocks).

#define GBM 128
#define LDT 56

__global__ __launch_bounds__(256) void gemm_kernel(const float* __restrict__ A,
                                                   const ushort* __restrict__ Wb,
                                                   ushort* __restrict__ P) {
    __shared__ __align__(16) ushort Ws[256][LDT];
    __shared__ __align__(16) ushort Fs[GBM][LDT];
    int t = threadIdx.x;
    int m0 = blockIdx.x * GBM;
    int w = t >> 6, lane = t & 63;
    int l15 = lane & 15, q = lane >> 4, q8 = q * 8;
    f32x4 acc[4][8] = {};
    int wf = t & 3, wr = t >> 2;   // W staging: 4x16B chunks per row
    int ff = t & 7, fr = t >> 3;   // F staging: 8x float4 per row
    int frow[4];
    #pragma unroll
    for (int p = 0; p < 4; ++p) {
        int gr = m0 + fr + p * 32;
        frow[p] = (gr >= N_NODES) ? (N_NODES - 1) : gr;
    }
    uint4 wreg[4];
    float4 freg[4];
    #pragma unroll
    for (int p = 0; p < 4; ++p) {
        wreg[p] = *(const uint4*)&Wb[(size_t)(wr + p * 64) * IN_CH + wf * 8];
        freg[p] = *(const float4*)&A[(size_t)frow[p] * IN_CH + ff * 4];
    }
    for (int k0 = 0; k0 < IN_CH; k0 += 32) {
        #pragma unroll
        for (int p = 0; p < 4; ++p) {
            *(uint4*)&Ws[wr + p * 64][wf * 8] = wreg[p];
            uint2 pk;
            pk.x = pkbf(freg[p].x, freg[p].y);
            pk.y = pkbf(freg[p].z, freg[p].w);
            *(uint2*)&Fs[fr + p * 32][ff * 4] = pk;
        }
        __syncthreads();
        int kn = k0 + 32;
        if (kn < IN_CH) {
            #pragma unroll
            for (int p = 0; p < 4; ++p) {
                wreg[p] = *(const uint4*)&Wb[(size_t)(wr + p * 64) * IN_CH + kn + wf * 8];
                freg[p] = *(const float4*)&A[(size_t)frow[p] * IN_CH + kn + ff * 4];
            }
        }
        bf16x8 bfr[8];
        #pragma unroll
        for (int nf = 0; nf < 8; ++nf)
            bfr[nf] = *(const bf16x8*)&Fs[nf * 16 + l15][q8];
        #pragma unroll
        for (int cf = 0; cf < 4; ++cf) {
            bf16x8 af = *(const bf16x8*)&Ws[w * 64 + cf * 16 + l15][q8];
            #pragma unroll
            for (int nf = 0; nf < 8; ++nf)
                acc[cf][nf] = __builtin_amdgcn_mfma_f32_16x16x32_bf16(af, bfr[nf], acc[cf][nf], 0, 0, 0);
        }
        __syncthreads();
    }
    #pragma unroll
    for (int nf = 0; nf < 8; ++nf) {
        int node = m0 + nf * 16 + l15;
        if (node < N_NODES) {
            #pragma unroll
            for (int cf = 0; cf < 4; ++cf) {
                f32x4 v = acc[cf][nf];
                uint2 pk;
                pk.x = pkbf(v[0], v[1]);
                pk.y = pkbf(v[2], v[3]);
                *(uint2*)&P[(size_t)node * 256 + w * 64 + cf * 16 + q * 4] = pk;
            }
        }
    }
}

// ---------------- fused gather + SAGE combine + MLP tail ----------------
// 512 threads = 8 waves per block, 4 nodes per block, 2 waves per node.
// col indices preloaded into lanes + shuffle-broadcast; gather unrolled x4.

__global__ __launch_bounds__(512) void fused_tail(const ushort* __restrict__ P,
                                                  const int* __restrict__ deg,
                                                  const int* __restrict__ row_start,
                                                  const int* __restrict__ col,
                                                  const float* __restrict__ addf,
                                                  const float* __restrict__ bl,
                                                  const float* __restrict__ W1t,
                                                  const float* __restrict__ b1,
                                                  const float* __restrict__ W2,
                                                  const float* __restrict__ b2,
                                                  const float* __restrict__ gamma,
                                                  const float* __restrict__ beta,
                                                  const float* __restrict__ rmean,
                                                  const float* __restrict__ rvar,
                                                  float* __restrict__ out) {
    __shared__ float part[8][130];
    __shared__ float xbuf[4][XCH + 4];
    __shared__ float hbuf[4][MID + 3];
    int w = threadIdx.x >> 6;
    int lane = threadIdx.x & 63;
    int slot = w >> 1, half = w & 1;
    int n = blockIdx.x * 4 + slot;
    float a0 = 0.f, a1 = 0.f;
    if (n < N_NODES) {
        int d = deg[n], st = row_start[n];
        int dh = d >> 1;
        int myst = st + (half ? dh : 0);
        int myd = half ? (d - dh) : dh;
        for (int base = 0; base < myd; base += 64) {
            int cnt = myd - base;
            if (cnt > 64) cnt = 64;
            int cidx = (lane < cnt) ? col[myst + base + lane] : 0;
            int i = 0;
            for (; i + 4 <= cnt; i += 4) {
                int s0 = __shfl(cidx, i);
                int s1 = __shfl(cidx, i + 1);
                int s2 = __shfl(cidx, i + 2);
                int s3 = __shfl(cidx, i + 3);
                unsigned int v0 = *(const unsigned int*)&P[(unsigned)s0 * 256 + lane * 2];
                unsigned int v1 = *(const unsigned int*)&P[(unsigned)s1 * 256 + lane * 2];
                unsigned int v2 = *(const unsigned int*)&P[(unsigned)s2 * 256 + lane * 2];
                unsigned int v3 = *(const unsigned int*)&P[(unsigned)s3 * 256 + lane * 2];
                a0 += bflo(v0) + bflo(v1) + bflo(v2) + bflo(v3);
                a1 += bfhi(v0) + bfhi(v1) + bfhi(v2) + bfhi(v3);
            }
            for (; i < cnt; ++i) {
                int s = __shfl(cidx, i);
                unsigned int v = *(const unsigned int*)&P[(unsigned)s * 256 + lane * 2];
                a0 += bflo(v);
                a1 += bfhi(v);
            }
        }
    }
    part[w][2 * lane] = a0;
    part[w][2 * lane + 1] = a1;
    __syncthreads();
    if (w < 4) {
        int n2 = blockIdx.x * 4 + w;
        if (n2 < N_NODES) {
            int d = deg[n2];
            float invd = 1.0f / (float)(d > 1 ? d : 1);
            float s0 = part[2 * w][2 * lane] + part[2 * w + 1][2 * lane];
            float s1 = part[2 * w][2 * lane + 1] + part[2 * w + 1][2 * lane + 1];
            unsigned int vr = *(const unsigned int*)&P[(unsigned)n2 * 256 + 128 + lane * 2];
            float x0 = s0 * invd + bl[2 * lane] + bflo(vr);
            float x1 = s1 * invd + bl[2 * lane + 1] + bfhi(vr);
            x0 = (x0 >= 0.f) ? x0 : 0.01f * x0;
            x1 = (x1 >= 0.f) ? x1 : 0.01f * x1;
            xbuf[w][2 * lane] = x0;
            xbuf[w][2 * lane + 1] = x1;
            if (lane < ADD_CH) xbuf[w][FC + lane] = addf[(size_t)n2 * ADD_CH + lane];
            // same-wave LDS write->read below; compiler inserts lgkmcnt waits
            if (lane < MID) {
                float h = b1[lane];
                #pragma unroll 4
                for (int k = 0; k < XCH; ++k) h += W1t[k * MID + lane] * xbuf[w][k];
                h = fmaxf(h, 0.0f);
                h = gamma[lane] * (h - rmean[lane]) * rsqrtf(rvar[lane] + 1e-5f) + beta[lane];
                hbuf[w][lane] = h;
            }
            if (lane < OUT_CH) {
                float o = b2[lane];
                #pragma unroll
                for (int j = 0; j < MID; ++j) o += W2[lane * MID + j] * hbuf[w][j];
                out[(size_t)n2 * OUT_CH + lane] = o;
            }
        }
    }
}

// ---------------- launch ----------------

extern "C" void kernel_launch(void* const* d_in, const int* in_sizes, int n_in,
                              void* d_out, int out_size, void* d_ws, size_t ws_size,
                              hipStream_t stream) {
    const float* features = (const float*)d_in[0];
    const int*   edges    = (const int*)d_in[1];
    const float* addf     = (const float*)d_in[4];
    const float* Wl       = (const float*)d_in[5];
    const float* bl       = (const float*)d_in[6];
    const float* Wr       = (const float*)d_in[7];
    const float* W1       = (const float*)d_in[8];
    const float* b1       = (const float*)d_in[9];
    const float* W2       = (const float*)d_in[10];
    const float* b2       = (const float*)d_in[11];
    const float* gamma    = (const float*)d_in[12];
    const float* beta     = (const float*)d_in[13];
    const float* rmean    = (const float*)d_in[14];
    const float* rvar     = (const float*)d_in[15];
    float* out = (float*)d_out;

    char* ws = (char*)d_ws;
    size_t off = 0;
    ushort* P = (ushort*)(ws + off);      off += (size_t)N_NODES * 256 * 2;   // 12.8 MB
    ushort* Wb = (ushort*)(ws + off);     off += (size_t)256 * IN_CH * 2;     // 512 KB
    int* deg = (int*)(ws + off);          off += (size_t)N_NODES * 4;
    int* cursor = (int*)(ws + off);       off += (size_t)N_NODES * 4;
    int* row_start = (int*)(ws + off);    off += (size_t)N_NODES * 4;
    int* col = (int*)(ws + off);          off += (size_t)N_EDGES * 4;
    float* W1t = (float*)(ws + off);      off += (size_t)MID * XCH * 4;

    (void)hipMemsetAsync(deg, 0, (size_t)2 * N_NODES * 4, stream);  // deg + cursor

    prep_kernel<<<256 + HIST_B + 1, 256, 0, stream>>>(Wl, Wr, edges, W1, Wb, deg, W1t);
    scan_kernel<<<1, 1024, 0, stream>>>(deg, row_start);
    fill_kernel<<<(N_EDGES + 255) / 256, 256, 0, stream>>>(edges, row_start, cursor, col);

    gemm_kernel<<<(N_NODES + GBM - 1) / GBM, 256, 0, stream>>>(features, Wb, P);

    fused_tail<<<(N_NODES + 3) / 4, 512, 0, stream>>>(P, deg, row_start, col, addf, bl,
                                                      W1t, b1, W2, b2, gamma, beta,
                                                      rmean, rvar, out);
}